// Round 1
// baseline (480.298 us; speedup 1.0000x reference)
//
#include <hip/hip_runtime.h>

#define B 128
#define S 200
#define LW 50
#define Q 20
#define V 50000
#define D 128
#define NH 3
#define VD (V * D)              // 6,400,000
#define BSD (B * S * D)         // 3,276,800

// ---------------------------------------------------------------------------
// G[k][b*S+s][d] = sum_l embs[k][story[b,s,l], d] * pe_s(l, d)   for k=0..3
// One block per (b,s); 128 threads = one d each. Index loads are block-uniform
// (scalar path); embedding row loads are fully coalesced (128 lanes x 4B).
// ---------------------------------------------------------------------------
__global__ __launch_bounds__(128) void k_gather_story(
    const int* __restrict__ story, const float* __restrict__ embs,
    float* __restrict__ G) {
  int bs = blockIdx.x;
  int d = threadIdx.x;
  const int* w = story + bs * LW;
  float kd = (float)(d + 1) / (float)D;
  float a0 = 0.f, a1 = 0.f, a2 = 0.f, a3 = 0.f;
  for (int l = 0; l < LW; ++l) {
    int idx = w[l];
    float jj = (float)(l + 1) / (float)LW;
    float pe = 1.0f - jj - kd * (1.0f - 2.0f * jj);
    size_t base = (size_t)idx * D + d;
    a0 += embs[base] * pe;
    a1 += embs[base + (size_t)VD] * pe;
    a2 += embs[base + (size_t)(2 * VD)] * pe;
    a3 += embs[base + (size_t)(3 * VD)] * pe;
  }
  size_t o = (size_t)bs * D + d;
  G[o] = a0;
  G[o + (size_t)BSD] = a1;
  G[o + (size_t)(2 * BSD)] = a2;
  G[o + (size_t)(3 * BSD)] = a3;
}

// ---------------------------------------------------------------------------
// u[b][d] = sum_q embs[0][query[b,q], d] * pe_q(q, d)
// ---------------------------------------------------------------------------
__global__ __launch_bounds__(128) void k_gather_query(
    const int* __restrict__ query, const float* __restrict__ embs,
    float* __restrict__ u) {
  int b = blockIdx.x;
  int d = threadIdx.x;
  float kd = (float)(d + 1) / (float)D;
  float acc = 0.f;
  for (int q = 0; q < Q; ++q) {
    int idx = query[b * Q + q];
    float jj = (float)(q + 1) / (float)Q;
    float pe = 1.0f - jj - kd * (1.0f - 2.0f * jj);
    acc += embs[(size_t)idx * D + d] * pe;
  }
  u[b * D + d] = acc;
}

// ---------------------------------------------------------------------------
// 3 attention hops. One block per b, 256 threads.
//   m = G[hop] + TA[hop]; c = G[hop+1] + TC[hop]
//   p = softmax(m @ u); u += p @ c
// ---------------------------------------------------------------------------
__global__ __launch_bounds__(256) void k_hops(
    const float* __restrict__ G, const float* __restrict__ TA,
    const float* __restrict__ TC, float* __restrict__ u) {
  __shared__ float su[D];
  __shared__ float sp[S];
  __shared__ float sred[2];
  int b = blockIdx.x;
  int t = threadIdx.x;
  if (t < D) su[t] = u[b * D + t];
  __syncthreads();
  for (int hop = 0; hop < NH; ++hop) {
    const float* Gm = G + (size_t)hop * BSD + (size_t)b * S * D;
    const float* Gc = G + (size_t)(hop + 1) * BSD + (size_t)b * S * D;
    const float* ta = TA + hop * S * D;
    const float* tc = TC + hop * S * D;
    if (t < S) {
      float sc = 0.f;
      for (int d = 0; d < D; ++d) sc += (Gm[t * D + d] + ta[t * D + d]) * su[d];
      sp[t] = sc;
    }
    __syncthreads();
    if (t < 64) {  // one wave reduces max and sum
      float mx = -1e30f;
      for (int s = t; s < S; s += 64) mx = fmaxf(mx, sp[s]);
#pragma unroll
      for (int off = 1; off < 64; off <<= 1) mx = fmaxf(mx, __shfl_xor(mx, off));
      float sum = 0.f;
      for (int s = t; s < S; s += 64) sum += expf(sp[s] - mx);
#pragma unroll
      for (int off = 1; off < 64; off <<= 1) sum += __shfl_xor(sum, off);
      if (t == 0) { sred[0] = mx; sred[1] = sum; }
    }
    __syncthreads();
    float mx = sred[0];
    float inv = 1.0f / sred[1];
    if (t < S) sp[t] = expf(sp[t] - mx) * inv;
    __syncthreads();
    if (t < D) {
      float o = 0.f;
      for (int s = 0; s < S; ++s) o += sp[s] * (Gc[s * D + t] + tc[s * D + t]);
      su[t] += o;
    }
    __syncthreads();
  }
  if (t < D) u[b * D + t] = su[t];
}

// ---------------------------------------------------------------------------
// logits[b][v] = sum_d u[b][d] * e3[v][d]
// Tile: 64 v-rows x 64 b-rows per block, 4x4 per-thread register tile.
// ---------------------------------------------------------------------------
__global__ __launch_bounds__(256) void k_logits(
    const float* __restrict__ u, const float* __restrict__ e3,
    float* __restrict__ out) {
  __shared__ float sE[64][129];
  __shared__ float sU[64][129];
  int v0 = blockIdx.x * 64;
  int b0 = blockIdx.y * 64;
  int t = threadIdx.x;
  for (int i = 0; i < 32; ++i) {
    int lin = i * 256 + t;
    int r = lin >> 7, c = lin & 127;
    int v = v0 + r;
    sE[r][c] = (v < V) ? e3[(size_t)v * D + c] : 0.f;
    sU[r][c] = u[(b0 + r) * D + c];
  }
  __syncthreads();
  int tv = (t & 15) * 4;
  int tb = (t >> 4) * 4;
  float acc[4][4] = {};
  for (int d = 0; d < D; ++d) {
    float ev[4], ub[4];
#pragma unroll
    for (int i = 0; i < 4; ++i) ev[i] = sE[tv + i][d];
#pragma unroll
    for (int j = 0; j < 4; ++j) ub[j] = sU[tb + j][d];
#pragma unroll
    for (int j = 0; j < 4; ++j)
#pragma unroll
      for (int i = 0; i < 4; ++i) acc[j][i] += ub[j] * ev[i];
  }
  for (int j = 0; j < 4; ++j)
    for (int i = 0; i < 4; ++i) {
      int v = v0 + tv + i;
      if (v < V) out[(size_t)(b0 + tb + j) * V + v] = acc[j][i];
    }
}

extern "C" void kernel_launch(void* const* d_in, const int* in_sizes, int n_in,
                              void* d_out, int out_size, void* d_ws,
                              size_t ws_size, hipStream_t stream) {
  (void)in_sizes; (void)n_in; (void)out_size; (void)ws_size;
  const int* story = (const int*)d_in[0];
  const int* query = (const int*)d_in[1];
  const float* embs = (const float*)d_in[2];
  const float* TA = (const float*)d_in[3];
  const float* TC = (const float*)d_in[4];
  float* out = (float*)d_out;

  float* G = (float*)d_ws;                    // 4 * BSD floats = 50.0 MiB
  float* u = G + 4 * (size_t)BSD;             // B * D floats

  k_gather_query<<<B, D, 0, stream>>>(query, embs, u);
  k_gather_story<<<B * S, D, 0, stream>>>(story, embs, G);
  k_hops<<<B, 256, 0, stream>>>(G, TA, TC, u);
  k_logits<<<dim3((V + 63) / 64, B / 64), 256, 0, stream>>>(
      u, embs + 3 * (size_t)VD, out);
}

// Round 2
// 323.428 us; speedup vs baseline: 1.4850x; 1.4850x over previous
//
#include <hip/hip_runtime.h>

#define B 128
#define S 200
#define LW 50
#define Q 20
#define V 50000
#define D 128
#define NH 3
#define VD (V * D)              // 6,400,000
#define BSD (B * S * D)        // 3,276,800

// ---- bf16 helpers (bit-level, RNE pack) -----------------------------------
__device__ __forceinline__ unsigned int f2bf_rne(float f) {
  union { float f; unsigned int u; } c; c.f = f;
  return (c.u + 0x7FFFu + ((c.u >> 16) & 1u)) >> 16;
}
__device__ __forceinline__ float bf_lo(unsigned int q) {
  union { unsigned int u; float f; } c; c.u = q << 16; return c.f;
}
__device__ __forceinline__ float bf_hi(unsigned int q) {
  union { unsigned int u; float f; } c; c.u = q & 0xFFFF0000u; return c.f;
}

// ---------------------------------------------------------------------------
// Repack: E4[v][l=dpair 0..63] = uint4{ pack(k=0), pack(k=1), pack(k=2),
// pack(k=3) } where pack(k) = bf16(embs[k][v][2l]) | bf16(embs[k][v][2l+1])<<16.
// One word's 4 table rows become ONE contiguous 1 KB block.
// Block = 256 threads = 4 v's (one wave each). Reads/writes fully coalesced.
// ---------------------------------------------------------------------------
__global__ __launch_bounds__(256) void k_repack(
    const float* __restrict__ embs, uint4* __restrict__ E4) {
  int v = blockIdx.x * 4 + (threadIdx.x >> 6);
  int l = threadIdx.x & 63;
  uint4 q;
  {
    const float2 e = *(const float2*)(embs + (size_t)0 * VD + (size_t)v * D + 2 * l);
    q.x = f2bf_rne(e.x) | (f2bf_rne(e.y) << 16);
  }
  {
    const float2 e = *(const float2*)(embs + (size_t)1 * VD + (size_t)v * D + 2 * l);
    q.y = f2bf_rne(e.x) | (f2bf_rne(e.y) << 16);
  }
  {
    const float2 e = *(const float2*)(embs + (size_t)2 * VD + (size_t)v * D + 2 * l);
    q.z = f2bf_rne(e.x) | (f2bf_rne(e.y) << 16);
  }
  {
    const float2 e = *(const float2*)(embs + (size_t)3 * VD + (size_t)v * D + 2 * l);
    q.w = f2bf_rne(e.x) | (f2bf_rne(e.y) << 16);
  }
  E4[(size_t)v * 64 + l] = q;
}

// ---------------------------------------------------------------------------
// Story gather from repacked bf16 table. One wave per (b,s); lane l owns
// d = 2l, 2l+1 for all 4 tables. One global_load_dwordx4 per word per lane.
// G kept f32: G2[k*BSD/2 + bs*64 + l] = float2(d=2l, d=2l+1).
// ---------------------------------------------------------------------------
__global__ __launch_bounds__(256) void k_gather_story_bf(
    const int* __restrict__ story, const uint4* __restrict__ E4,
    float2* __restrict__ G2) {
  int bs = blockIdx.x * 4 + (threadIdx.x >> 6);
  int l = threadIdx.x & 63;
  const int* w = story + bs * LW;
  float c0 = (float)(2 * l + 1) / (float)D;
  float c1 = (float)(2 * l + 2) / (float)D;
  float a00 = 0.f, a01 = 0.f, a10 = 0.f, a11 = 0.f;
  float a20 = 0.f, a21 = 0.f, a30 = 0.f, a31 = 0.f;
  for (int j = 0; j < LW; ++j) {
    int idx = w[j];
    float jj = (float)(j + 1) / (float)LW;
    float a = 1.0f - jj;
    float bb = -(1.0f - 2.0f * jj);
    float pe0 = a + bb * c0;
    float pe1 = a + bb * c1;
    uint4 q = E4[(size_t)idx * 64 + l];
    a00 += bf_lo(q.x) * pe0; a01 += bf_hi(q.x) * pe1;
    a10 += bf_lo(q.y) * pe0; a11 += bf_hi(q.y) * pe1;
    a20 += bf_lo(q.z) * pe0; a21 += bf_hi(q.z) * pe1;
    a30 += bf_lo(q.w) * pe0; a31 += bf_hi(q.w) * pe1;
  }
  size_t o = (size_t)bs * 64 + l;
  G2[o] = make_float2(a00, a01);
  G2[o + (size_t)(BSD / 2)] = make_float2(a10, a11);
  G2[o + (size_t)(2 * (BSD / 2))] = make_float2(a20, a21);
  G2[o + (size_t)(3 * (BSD / 2))] = make_float2(a30, a31);
}

// ---------------------------------------------------------------------------
// Fallback f32 story gather (round-1 path, used only if ws too small).
// ---------------------------------------------------------------------------
__global__ __launch_bounds__(128) void k_gather_story(
    const int* __restrict__ story, const float* __restrict__ embs,
    float* __restrict__ G) {
  int bs = blockIdx.x;
  int d = threadIdx.x;
  const int* w = story + bs * LW;
  float kd = (float)(d + 1) / (float)D;
  float a0 = 0.f, a1 = 0.f, a2 = 0.f, a3 = 0.f;
  for (int l = 0; l < LW; ++l) {
    int idx = w[l];
    float jj = (float)(l + 1) / (float)LW;
    float pe = 1.0f - jj - kd * (1.0f - 2.0f * jj);
    size_t base = (size_t)idx * D + d;
    a0 += embs[base] * pe;
    a1 += embs[base + (size_t)VD] * pe;
    a2 += embs[base + (size_t)(2 * VD)] * pe;
    a3 += embs[base + (size_t)(3 * VD)] * pe;
  }
  size_t o = (size_t)bs * D + d;
  G[o] = a0;
  G[o + (size_t)BSD] = a1;
  G[o + (size_t)(2 * BSD)] = a2;
  G[o + (size_t)(3 * BSD)] = a3;
}

// ---------------------------------------------------------------------------
// u[b][d] = sum_q embs[0][query[b,q], d] * pe_q(q, d)
// ---------------------------------------------------------------------------
__global__ __launch_bounds__(128) void k_gather_query(
    const int* __restrict__ query, const float* __restrict__ embs,
    float* __restrict__ u) {
  int b = blockIdx.x;
  int d = threadIdx.x;
  float kd = (float)(d + 1) / (float)D;
  float acc = 0.f;
  for (int q = 0; q < Q; ++q) {
    int idx = query[b * Q + q];
    float jj = (float)(q + 1) / (float)Q;
    float pe = 1.0f - jj - kd * (1.0f - 2.0f * jj);
    acc += embs[(size_t)idx * D + d] * pe;
  }
  u[b * D + d] = acc;
}

// ---------------------------------------------------------------------------
// 3 attention hops. One block per b, 256 threads.
// ---------------------------------------------------------------------------
__global__ __launch_bounds__(256) void k_hops(
    const float* __restrict__ G, const float* __restrict__ TA,
    const float* __restrict__ TC, float* __restrict__ u) {
  __shared__ float su[D];
  __shared__ float sp[S];
  __shared__ float sred[2];
  int b = blockIdx.x;
  int t = threadIdx.x;
  if (t < D) su[t] = u[b * D + t];
  __syncthreads();
  for (int hop = 0; hop < NH; ++hop) {
    const float* Gm = G + (size_t)hop * BSD + (size_t)b * S * D;
    const float* Gc = G + (size_t)(hop + 1) * BSD + (size_t)b * S * D;
    const float* ta = TA + hop * S * D;
    const float* tc = TC + hop * S * D;
    if (t < S) {
      float sc = 0.f;
      for (int d = 0; d < D; ++d) sc += (Gm[t * D + d] + ta[t * D + d]) * su[d];
      sp[t] = sc;
    }
    __syncthreads();
    if (t < 64) {
      float mx = -1e30f;
      for (int s = t; s < S; s += 64) mx = fmaxf(mx, sp[s]);
#pragma unroll
      for (int off = 1; off < 64; off <<= 1) mx = fmaxf(mx, __shfl_xor(mx, off));
      float sum = 0.f;
      for (int s = t; s < S; s += 64) sum += expf(sp[s] - mx);
#pragma unroll
      for (int off = 1; off < 64; off <<= 1) sum += __shfl_xor(sum, off);
      if (t == 0) { sred[0] = mx; sred[1] = sum; }
    }
    __syncthreads();
    float mx = sred[0];
    float inv = 1.0f / sred[1];
    if (t < S) sp[t] = expf(sp[t] - mx) * inv;
    __syncthreads();
    if (t < D) {
      float o = 0.f;
      for (int s = 0; s < S; ++s) o += sp[s] * (Gc[s * D + t] + tc[s * D + t]);
      su[t] += o;
    }
    __syncthreads();
  }
  if (t < D) u[b * D + t] = su[t];
}

// ---------------------------------------------------------------------------
// logits[b][v] = sum_d u[b][d] * e3[v][d]  (f32 vector path)
// ---------------------------------------------------------------------------
__global__ __launch_bounds__(256) void k_logits(
    const float* __restrict__ u, const float* __restrict__ e3,
    float* __restrict__ out) {
  __shared__ float sE[64][129];
  __shared__ float sU[64][129];
  int v0 = blockIdx.x * 64;
  int b0 = blockIdx.y * 64;
  int t = threadIdx.x;
  for (int i = 0; i < 32; ++i) {
    int lin = i * 256 + t;
    int r = lin >> 7, c = lin & 127;
    int v = v0 + r;
    sE[r][c] = (v < V) ? e3[(size_t)v * D + c] : 0.f;
    sU[r][c] = u[(b0 + r) * D + c];
  }
  __syncthreads();
  int tv = (t & 15) * 4;
  int tb = (t >> 4) * 4;
  float acc[4][4] = {};
  for (int d = 0; d < D; ++d) {
    float ev[4], ub[4];
#pragma unroll
    for (int i = 0; i < 4; ++i) ev[i] = sE[tv + i][d];
#pragma unroll
    for (int j = 0; j < 4; ++j) ub[j] = sU[tb + j][d];
#pragma unroll
    for (int j = 0; j < 4; ++j)
#pragma unroll
      for (int i = 0; i < 4; ++i) acc[j][i] += ub[j] * ev[i];
  }
  for (int j = 0; j < 4; ++j)
    for (int i = 0; i < 4; ++i) {
      int v = v0 + tv + i;
      if (v < V) out[(size_t)(b0 + tb + j) * V + v] = acc[j][i];
    }
}

extern "C" void kernel_launch(void* const* d_in, const int* in_sizes, int n_in,
                              void* d_out, int out_size, void* d_ws,
                              size_t ws_size, hipStream_t stream) {
  (void)in_sizes; (void)n_in; (void)out_size;
  const int* story = (const int*)d_in[0];
  const int* query = (const int*)d_in[1];
  const float* embs = (const float*)d_in[2];
  const float* TA = (const float*)d_in[3];
  const float* TC = (const float*)d_in[4];
  float* out = (float*)d_out;

  const size_t e4_bytes = (size_t)V * 64 * sizeof(uint4);   // 51.2 MB
  const size_t g_bytes = (size_t)4 * BSD * sizeof(float);   // 52.4 MB
  const size_t u_bytes = (size_t)B * D * sizeof(float);

  if (ws_size >= e4_bytes + g_bytes + u_bytes) {
    // bf16 repacked path
    uint4* E4 = (uint4*)d_ws;
    float* G = (float*)((char*)d_ws + e4_bytes);
    float* u = (float*)((char*)d_ws + e4_bytes + g_bytes);

    k_repack<<<V / 4, 256, 0, stream>>>(embs, E4);
    k_gather_query<<<B, D, 0, stream>>>(query, embs, u);
    k_gather_story_bf<<<B * S / 4, 256, 0, stream>>>(story, E4, (float2*)G);
    k_hops<<<B, 256, 0, stream>>>(G, TA, TC, u);
    k_logits<<<dim3((V + 63) / 64, B / 64), 256, 0, stream>>>(
        u, embs + 3 * (size_t)VD, out);
  } else {
    // round-1 fallback
    float* G = (float*)d_ws;
    float* u = G + 4 * (size_t)BSD;
    k_gather_query<<<B, D, 0, stream>>>(query, embs, u);
    k_gather_story<<<B * S, D, 0, stream>>>(story, embs, G);
    k_hops<<<B, 256, 0, stream>>>(G, TA, TC, u);
    k_logits<<<dim3((V + 63) / 64, B / 64), 256, 0, stream>>>(
        u, embs + 3 * (size_t)VD, out);
  }
}

// Round 3
// 262.680 us; speedup vs baseline: 1.8285x; 1.2313x over previous
//
#include <hip/hip_runtime.h>

#define B 128
#define S 200
#define LW 50
#define Q 20
#define V 50000
#define D 128
#define NH 3
#define VD (V * D)              // 6,400,000
#define BSD (B * S * D)        // 3,276,800
#define BS (B * S)             // 25,600

typedef __bf16 bf16x8 __attribute__((ext_vector_type(8)));
typedef float f32x4 __attribute__((ext_vector_type(4)));

// ---- bf16 helpers (bit-level, RNE pack) -----------------------------------
__device__ __forceinline__ unsigned int f2bf_rne(float f) {
  union { float f; unsigned int u; } c; c.f = f;
  return (c.u + 0x7FFFu + ((c.u >> 16) & 1u)) >> 16;
}
__device__ __forceinline__ unsigned int pack2(float a, float b) {
  return f2bf_rne(a) | (f2bf_rne(b) << 16);
}
__device__ __forceinline__ float bf_lo(unsigned int q) {
  union { unsigned int u; float f; } c; c.u = q << 16; return c.f;
}
__device__ __forceinline__ float bf_hi(unsigned int q) {
  union { unsigned int u; float f; } c; c.u = q & 0xFFFF0000u; return c.f;
}

// ---------------------------------------------------------------------------
// Repack: E4[v][l] = uint4{ pack(k=0), pack(k=1), pack(k=2), pack(k=3) },
// pack(k) = bf16 pair of embs[k][v][2l], [2l+1]. Also E3u[v][l] = pack(k=3)
// giving a contiguous bf16 [V][D] copy of embs[3] for the MFMA logits GEMM.
// ---------------------------------------------------------------------------
__global__ __launch_bounds__(256) void k_repack(
    const float* __restrict__ embs, uint4* __restrict__ E4,
    unsigned int* __restrict__ E3u) {
  int v = blockIdx.x * 4 + (threadIdx.x >> 6);
  int l = threadIdx.x & 63;
  uint4 q;
  {
    const float2 e = *(const float2*)(embs + (size_t)0 * VD + (size_t)v * D + 2 * l);
    q.x = pack2(e.x, e.y);
  }
  {
    const float2 e = *(const float2*)(embs + (size_t)1 * VD + (size_t)v * D + 2 * l);
    q.y = pack2(e.x, e.y);
  }
  {
    const float2 e = *(const float2*)(embs + (size_t)2 * VD + (size_t)v * D + 2 * l);
    q.z = pack2(e.x, e.y);
  }
  {
    const float2 e = *(const float2*)(embs + (size_t)3 * VD + (size_t)v * D + 2 * l);
    q.w = pack2(e.x, e.y);
  }
  E4[(size_t)v * 64 + l] = q;
  E3u[(size_t)v * 64 + l] = q.w;
}

// ---------------------------------------------------------------------------
// Story gather -> bf16 G. One wave per (b,s); lane l owns d = 2l, 2l+1 for
// all 4 tables. 2 words per iter => 2 row-loads in flight (MLP probe).
// Gp[k*BS*64 + bs*64 + l] = packed bf16 pair (d=2l, 2l+1) of table k's sum.
// ---------------------------------------------------------------------------
__global__ __launch_bounds__(256) void k_gather_story_bf(
    const int* __restrict__ story, const uint4* __restrict__ E4,
    unsigned int* __restrict__ Gp) {
  int bs = blockIdx.x * 4 + (threadIdx.x >> 6);
  int l = threadIdx.x & 63;
  const int* w = story + bs * LW;
  float c0 = (float)(2 * l + 1) / (float)D;
  float c1 = (float)(2 * l + 2) / (float)D;
  float a00 = 0.f, a01 = 0.f, a10 = 0.f, a11 = 0.f;
  float a20 = 0.f, a21 = 0.f, a30 = 0.f, a31 = 0.f;
#pragma unroll
  for (int j = 0; j < LW; j += 2) {
    int ia = w[j];
    int ib = w[j + 1];
    uint4 qa = E4[(size_t)ia * 64 + l];
    uint4 qb = E4[(size_t)ib * 64 + l];
    float ja = (float)(j + 1) / (float)LW;
    float aa = 1.0f - ja, ba = -(1.0f - 2.0f * ja);
    float pa0 = aa + ba * c0, pa1 = aa + ba * c1;
    float jb = (float)(j + 2) / (float)LW;
    float ab = 1.0f - jb, bb = -(1.0f - 2.0f * jb);
    float pb0 = ab + bb * c0, pb1 = ab + bb * c1;
    a00 += bf_lo(qa.x) * pa0; a01 += bf_hi(qa.x) * pa1;
    a10 += bf_lo(qa.y) * pa0; a11 += bf_hi(qa.y) * pa1;
    a20 += bf_lo(qa.z) * pa0; a21 += bf_hi(qa.z) * pa1;
    a30 += bf_lo(qa.w) * pa0; a31 += bf_hi(qa.w) * pa1;
    a00 += bf_lo(qb.x) * pb0; a01 += bf_hi(qb.x) * pb1;
    a10 += bf_lo(qb.y) * pb0; a11 += bf_hi(qb.y) * pb1;
    a20 += bf_lo(qb.z) * pb0; a21 += bf_hi(qb.z) * pb1;
    a30 += bf_lo(qb.w) * pb0; a31 += bf_hi(qb.w) * pb1;
  }
  size_t o = (size_t)bs * 64 + l;
  Gp[o] = pack2(a00, a01);
  Gp[o + (size_t)(BS * 64)] = pack2(a10, a11);
  Gp[o + (size_t)(2 * BS * 64)] = pack2(a20, a21);
  Gp[o + (size_t)(3 * BS * 64)] = pack2(a30, a31);
}

// ---------------------------------------------------------------------------
// u[b][d] = sum_q embs[0][query[b,q], d] * pe_q(q, d)   (f32 path, tiny)
// ---------------------------------------------------------------------------
__global__ __launch_bounds__(128) void k_gather_query(
    const int* __restrict__ query, const float* __restrict__ embs,
    float* __restrict__ u) {
  int b = blockIdx.x;
  int d = threadIdx.x;
  float kd = (float)(d + 1) / (float)D;
  float acc = 0.f;
  for (int q = 0; q < Q; ++q) {
    int idx = query[b * Q + q];
    float jj = (float)(q + 1) / (float)Q;
    float pe = 1.0f - jj - kd * (1.0f - 2.0f * jj);
    acc += embs[(size_t)idx * D + d] * pe;
  }
  u[b * D + d] = acc;
}

// ---------------------------------------------------------------------------
// 3 attention hops over bf16 G. One block per b, 256 threads.
// Score pass: thread t = sentence, uint2 (4 d) per iter.
// Weighted pass: 8 groups x 32 cols (float4 of d), LDS tree combine.
// ---------------------------------------------------------------------------
__global__ __launch_bounds__(256) void k_hops(
    const unsigned int* __restrict__ G, const float* __restrict__ TA,
    const float* __restrict__ TC, float* __restrict__ u) {
  __shared__ float su[D];
  __shared__ float sp[S];
  __shared__ float sred[2];
  __shared__ float4 oacc[8][32];
  int b = blockIdx.x;
  int t = threadIdx.x;
  if (t < D) su[t] = u[b * D + t];
  __syncthreads();
  for (int hop = 0; hop < NH; ++hop) {
    const unsigned int* Gm = G + ((size_t)hop * BS + (size_t)b * S) * 64;
    const unsigned int* Gc = G + ((size_t)(hop + 1) * BS + (size_t)b * S) * 64;
    const float* ta = TA + hop * S * D;
    const float* tc = TC + hop * S * D;
    if (t < S) {
      float sc = 0.f;
#pragma unroll 8
      for (int c = 0; c < 64; c += 2) {
        uint2 g2 = *(const uint2*)(Gm + (size_t)t * 64 + c);
        float4 t4 = *(const float4*)(ta + (size_t)t * D + 2 * c);
        sc += (bf_lo(g2.x) + t4.x) * su[2 * c + 0];
        sc += (bf_hi(g2.x) + t4.y) * su[2 * c + 1];
        sc += (bf_lo(g2.y) + t4.z) * su[2 * c + 2];
        sc += (bf_hi(g2.y) + t4.w) * su[2 * c + 3];
      }
      sp[t] = sc;
    }
    __syncthreads();
    if (t < 64) {
      float mx = -1e30f;
      for (int s = t; s < S; s += 64) mx = fmaxf(mx, sp[s]);
#pragma unroll
      for (int off = 1; off < 64; off <<= 1) mx = fmaxf(mx, __shfl_xor(mx, off));
      float sum = 0.f;
      for (int s = t; s < S; s += 64) sum += expf(sp[s] - mx);
#pragma unroll
      for (int off = 1; off < 64; off <<= 1) sum += __shfl_xor(sum, off);
      if (t == 0) { sred[0] = mx; sred[1] = sum; }
    }
    __syncthreads();
    float mx = sred[0];
    float inv = 1.0f / sred[1];
    if (t < S) sp[t] = expf(sp[t] - mx) * inv;
    __syncthreads();
    {
      int g = t >> 5, c = t & 31;
      float4 o4 = {0.f, 0.f, 0.f, 0.f};
      for (int s = g; s < S; s += 8) {
        float p = sp[s];
        uint2 g2 = *(const uint2*)(Gc + (size_t)s * 64 + 2 * c);
        float4 t4 = *(const float4*)(tc + (size_t)s * D + 4 * c);
        o4.x += p * (bf_lo(g2.x) + t4.x);
        o4.y += p * (bf_hi(g2.x) + t4.y);
        o4.z += p * (bf_lo(g2.y) + t4.z);
        o4.w += p * (bf_hi(g2.y) + t4.w);
      }
      oacc[g][c] = o4;
    }
    __syncthreads();
    if (t < 32) {
      float4 o = oacc[0][t];
#pragma unroll
      for (int g = 1; g < 8; ++g) {
        float4 x = oacc[g][t];
        o.x += x.x; o.y += x.y; o.z += x.z; o.w += x.w;
      }
      su[4 * t + 0] += o.x;
      su[4 * t + 1] += o.y;
      su[4 * t + 2] += o.z;
      su[4 * t + 3] += o.w;
    }
    __syncthreads();
  }
  if (t < D) u[b * D + t] = su[t];
}

// ---------------------------------------------------------------------------
// u (f32 [B][D]) -> packed bf16 pairs [B][64]
// ---------------------------------------------------------------------------
__global__ __launch_bounds__(256) void k_u2bf(
    const float* __restrict__ u, unsigned int* __restrict__ ubf) {
  int i = blockIdx.x * 256 + threadIdx.x;  // 0 .. B*64-1
  ubf[i] = pack2(u[2 * i], u[2 * i + 1]);
}

// ---------------------------------------------------------------------------
// logits[b][v] = sum_d u[b][d] * e3[v][d] via mfma_f32_16x16x32_bf16.
// A = u_bf (M=batch x K=128), B = e3^T (K x N=v). Wave covers 32 v x 128 b.
// Block = 4 waves = 128 v. Fragment layout (m89-verified):
//   A: row=lane&15, k=(lane>>4)*8+j ; B: col=lane&15, same k
//   D: col=lane&15 (v), row=(lane>>4)*4+r (batch)
// ---------------------------------------------------------------------------
__global__ __launch_bounds__(256) void k_logits_mfma(
    const uint4* __restrict__ ubf,   // [B][16] uint4 (=128 bf16 per row)
    const uint4* __restrict__ e3u,   // [V][16]
    float* __restrict__ out) {
  int wid = threadIdx.x >> 6;
  int l = threadIdx.x & 63;
  int lr = l & 15;
  int lk = l >> 4;
  int vbase = blockIdx.x * 128 + wid * 32;
  uint4 bfrag[2][4];
#pragma unroll
  for (int vs = 0; vs < 2; ++vs) {
    int v = vbase + vs * 16 + lr;
    if (v >= V) v = V - 1;  // clamp loads; stores guarded
#pragma unroll
    for (int kk = 0; kk < 4; ++kk)
      bfrag[vs][kk] = e3u[(size_t)v * 16 + kk * 4 + lk];
  }
  f32x4 acc[2][8];
#pragma unroll
  for (int vs = 0; vs < 2; ++vs)
#pragma unroll
    for (int m = 0; m < 8; ++m) {
      f32x4 z = {0.f, 0.f, 0.f, 0.f};
      acc[vs][m] = z;
    }
#pragma unroll
  for (int m = 0; m < 8; ++m) {
    uint4 afrag[4];
#pragma unroll
    for (int kk = 0; kk < 4; ++kk)
      afrag[kk] = ubf[(m * 16 + lr) * 16 + kk * 4 + lk];
#pragma unroll
    for (int vs = 0; vs < 2; ++vs)
#pragma unroll
      for (int kk = 0; kk < 4; ++kk)
        acc[vs][m] = __builtin_amdgcn_mfma_f32_16x16x32_bf16(
            __builtin_bit_cast(bf16x8, afrag[kk]),
            __builtin_bit_cast(bf16x8, bfrag[vs][kk]), acc[vs][m], 0, 0, 0);
  }
#pragma unroll
  for (int vs = 0; vs < 2; ++vs) {
    int v = vbase + vs * 16 + lr;
    if (v < V) {
#pragma unroll
      for (int m = 0; m < 8; ++m)
#pragma unroll
        for (int r = 0; r < 4; ++r)
          out[(size_t)(m * 16 + lk * 4 + r) * V + v] = acc[vs][m][r];
    }
  }
}

// ---------------------------------------------------------------------------
// Round-1 fallback kernels (f32, used only if ws too small)
// ---------------------------------------------------------------------------
__global__ __launch_bounds__(128) void k_gather_story(
    const int* __restrict__ story, const float* __restrict__ embs,
    float* __restrict__ G) {
  int bs = blockIdx.x;
  int d = threadIdx.x;
  const int* w = story + bs * LW;
  float kd = (float)(d + 1) / (float)D;
  float a0 = 0.f, a1 = 0.f, a2 = 0.f, a3 = 0.f;
  for (int l = 0; l < LW; ++l) {
    int idx = w[l];
    float jj = (float)(l + 1) / (float)LW;
    float pe = 1.0f - jj - kd * (1.0f - 2.0f * jj);
    size_t base = (size_t)idx * D + d;
    a0 += embs[base] * pe;
    a1 += embs[base + (size_t)VD] * pe;
    a2 += embs[base + (size_t)(2 * VD)] * pe;
    a3 += embs[base + (size_t)(3 * VD)] * pe;
  }
  size_t o = (size_t)bs * D + d;
  G[o] = a0;
  G[o + (size_t)BSD] = a1;
  G[o + (size_t)(2 * BSD)] = a2;
  G[o + (size_t)(3 * BSD)] = a3;
}

__global__ __launch_bounds__(256) void k_hops_f32(
    const float* __restrict__ G, const float* __restrict__ TA,
    const float* __restrict__ TC, float* __restrict__ u) {
  __shared__ float su[D];
  __shared__ float sp[S];
  __shared__ float sred[2];
  int b = blockIdx.x;
  int t = threadIdx.x;
  if (t < D) su[t] = u[b * D + t];
  __syncthreads();
  for (int hop = 0; hop < NH; ++hop) {
    const float* Gm = G + (size_t)hop * BSD + (size_t)b * S * D;
    const float* Gc = G + (size_t)(hop + 1) * BSD + (size_t)b * S * D;
    const float* ta = TA + hop * S * D;
    const float* tc = TC + hop * S * D;
    if (t < S) {
      float sc = 0.f;
      for (int d = 0; d < D; ++d) sc += (Gm[t * D + d] + ta[t * D + d]) * su[d];
      sp[t] = sc;
    }
    __syncthreads();
    if (t < 64) {
      float mx = -1e30f;
      for (int s = t; s < S; s += 64) mx = fmaxf(mx, sp[s]);
#pragma unroll
      for (int off = 1; off < 64; off <<= 1) mx = fmaxf(mx, __shfl_xor(mx, off));
      float sum = 0.f;
      for (int s = t; s < S; s += 64) sum += expf(sp[s] - mx);
#pragma unroll
      for (int off = 1; off < 64; off <<= 1) sum += __shfl_xor(sum, off);
      if (t == 0) { sred[0] = mx; sred[1] = sum; }
    }
    __syncthreads();
    float mx = sred[0];
    float inv = 1.0f / sred[1];
    if (t < S) sp[t] = expf(sp[t] - mx) * inv;
    __syncthreads();
    if (t < D) {
      float o = 0.f;
      for (int s = 0; s < S; ++s) o += sp[s] * (Gc[s * D + t] + tc[s * D + t]);
      su[t] += o;
    }
    __syncthreads();
  }
  if (t < D) u[b * D + t] = su[t];
}

__global__ __launch_bounds__(256) void k_logits_f32(
    const float* __restrict__ u, const float* __restrict__ e3,
    float* __restrict__ out) {
  __shared__ float sE[64][129];
  __shared__ float sU[64][129];
  int v0 = blockIdx.x * 64;
  int b0 = blockIdx.y * 64;
  int t = threadIdx.x;
  for (int i = 0; i < 32; ++i) {
    int lin = i * 256 + t;
    int r = lin >> 7, c = lin & 127;
    int v = v0 + r;
    sE[r][c] = (v < V) ? e3[(size_t)v * D + c] : 0.f;
    sU[r][c] = u[(b0 + r) * D + c];
  }
  __syncthreads();
  int tv = (t & 15) * 4;
  int tb = (t >> 4) * 4;
  float acc[4][4] = {};
  for (int d = 0; d < D; ++d) {
    float ev[4], ub[4];
#pragma unroll
    for (int i = 0; i < 4; ++i) ev[i] = sE[tv + i][d];
#pragma unroll
    for (int j = 0; j < 4; ++j) ub[j] = sU[tb + j][d];
#pragma unroll
    for (int j = 0; j < 4; ++j)
#pragma unroll
      for (int i = 0; i < 4; ++i) acc[j][i] += ub[j] * ev[i];
  }
  for (int j = 0; j < 4; ++j)
    for (int i = 0; i < 4; ++i) {
      int v = v0 + tv + i;
      if (v < V) out[(size_t)(b0 + tb + j) * V + v] = acc[j][i];
    }
}

extern "C" void kernel_launch(void* const* d_in, const int* in_sizes, int n_in,
                              void* d_out, int out_size, void* d_ws,
                              size_t ws_size, hipStream_t stream) {
  (void)in_sizes; (void)n_in; (void)out_size;
  const int* story = (const int*)d_in[0];
  const int* query = (const int*)d_in[1];
  const float* embs = (const float*)d_in[2];
  const float* TA = (const float*)d_in[3];
  const float* TC = (const float*)d_in[4];
  float* out = (float*)d_out;

  const size_t e4_bytes = (size_t)V * 64 * sizeof(uint4);        // 51.2 MB
  const size_t e3_bytes = (size_t)V * 64 * sizeof(unsigned int); // 12.8 MB
  const size_t g_bytes = (size_t)4 * BS * 64 * sizeof(unsigned int); // 26.2 MB
  const size_t u_bytes = (size_t)B * D * sizeof(float);
  const size_t ub_bytes = (size_t)B * 64 * sizeof(unsigned int);

  if (ws_size >= e4_bytes + e3_bytes + g_bytes + u_bytes + ub_bytes) {
    char* p = (char*)d_ws;
    uint4* E4 = (uint4*)p;                 p += e4_bytes;
    unsigned int* E3u = (unsigned int*)p;  p += e3_bytes;
    unsigned int* Gp = (unsigned int*)p;   p += g_bytes;
    float* u = (float*)p;                  p += u_bytes;
    unsigned int* ubf = (unsigned int*)p;

    k_repack<<<V / 4, 256, 0, stream>>>(embs, E4, E3u);
    k_gather_query<<<B, D, 0, stream>>>(query, embs, u);
    k_gather_story_bf<<<BS / 4, 256, 0, stream>>>(story, E4, Gp);
    k_hops<<<B, 256, 0, stream>>>(Gp, TA, TC, u);
    k_u2bf<<<B * 64 / 256, 256, 0, stream>>>(u, ubf);
    k_logits_mfma<<<(V + 127) / 128, 256, 0, stream>>>(
        (const uint4*)ubf, (const uint4*)E3u, out);
  } else {
    float* G = (float*)d_ws;
    float* u = G + 4 * (size_t)BSD;
    k_gather_query<<<B, D, 0, stream>>>(query, embs, u);
    k_gather_story<<<B * S, D, 0, stream>>>(story, embs, G);
    k_hops_f32<<<B, 256, 0, stream>>>(G, TA, TC, u);
    k_logits_f32<<<dim3((V + 63) / 64, B / 64), 256, 0, stream>>>(
        u, embs + 3 * (size_t)VD, out);
  }
}